// Round 6
// baseline (11582.513 us; speedup 1.0000x reference)
//
#include <hip/hip_runtime.h>
#include <hip/hip_bf16.h>

#define BB 32
#define SS 64
#define TT 63
#define EMBD 512
#define ENCD 1024
#define HIDD 1024
#define VV 32000
#define INTERD 2160
#define LIND 2560
#define TV (TT*VV)
#define OUT_ATT ((long)BB*TT*VV)

typedef float f32;
typedef unsigned short ushort_t;
typedef unsigned long long u64;
typedef __attribute__((ext_vector_type(8))) short bf16x8;
typedef __attribute__((ext_vector_type(4))) float f32x4;
typedef __attribute__((ext_vector_type(8))) unsigned short u16x8;
typedef __attribute__((ext_vector_type(4))) unsigned short u16x4;

// ---- ws layout (bytes) ----
#define OFF_LIN   0L
#define OFF_WD    20643840L
#define OFF_WHH0  (OFF_WD + 2097152L)
#define OFF_WIH0C (OFF_WHH0 + 8388608L)
#define OFF_WIH1  (OFF_WIH0C + 8388608L)
#define OFF_WHH1  (OFF_WIH1 + 8388608L)
#define OFF_WEND  (OFF_WHH1 + 8388608L)       /* 56,295,424 */
#define OFF_EG    OFF_WEND                     /* embgate bf16 2048x4096 = 16 MB */
#define OFF_ENCF  OFF_EG                       /* enc frags 4MB, pre-embgate only */
#define OFF_WET   (OFF_EG + 4194304L)          /* We^T frags 2MB, pre-embgate only */
#define OFF_EPB   (OFF_EG + 16777216L)         /* enc_proj bf16 4 MB */
#define OFF_EOB   (OFF_EPB + 4194304L)         /* enc_out  bf16 4 MB */
#define OFF_EMBF  (OFF_EOB + 4194304L)         /* emb frags 2 MB */
#define OFF_HWD   (OFF_EMBF + 2097152L)        /* f32 32x1024 (UC) */
#define OFF_C0    (OFF_HWD + 131072L)
#define OFF_C1    (OFF_C0 + 131072L)
#define OFF_H0F   (OFF_C1 + 131072L)           /* bf16 frags (UC) */
#define OFF_H1F   (OFF_H0F + 65536L)
#define OFF_CTXF  (OFF_H1F + 65536L)
#define OFF_CNT   (OFF_CTXF + 65536L)
#define OFF_LINBF OFF_WD                        /* post-loop aliases */
#define OFF_HIDBF (OFF_WD + 10485760L)

__device__ __forceinline__ f32 fast_tanh(f32 x){
    f32 e = __expf(2.0f*x);
    return 1.0f - 2.0f/(e+1.0f);
}
__device__ __forceinline__ f32 fast_sig(f32 x){
    return 1.0f/(1.0f+__expf(-x));
}
__device__ __forceinline__ ushort_t f2bf(f32 x){
    __hip_bfloat16 h = __float2bfloat16(x);
    return *(ushort_t*)&h;
}
__device__ __forceinline__ f32 bf2f(ushort_t u){
    unsigned v = ((unsigned)u) << 16;
    return __uint_as_float(v);
}
// ---- device-scope (LLC-coherent, L2-bypass) accessors ----
__device__ __forceinline__ u64 uc_ld8(const u64* p){
  return __hip_atomic_load(p, __ATOMIC_RELAXED, __HIP_MEMORY_SCOPE_AGENT);
}
__device__ __forceinline__ f32 uc_ld4f(const f32* p){
  return __hip_atomic_load(p, __ATOMIC_RELAXED, __HIP_MEMORY_SCOPE_AGENT);
}
__device__ __forceinline__ void uc_st8(u64* p, u64 v){
  __hip_atomic_store(p, v, __ATOMIC_RELAXED, __HIP_MEMORY_SCOPE_AGENT);
}
__device__ __forceinline__ void uc_st4f(f32* p, f32 v){
  __hip_atomic_store(p, v, __ATOMIC_RELAXED, __HIP_MEMORY_SCOPE_AGENT);
}
__device__ __forceinline__ void uc_st2(ushort_t* p, ushort_t v){
  __hip_atomic_store(p, v, __ATOMIC_RELAXED, __HIP_MEMORY_SCOPE_AGENT);
}

// A-fragment element index for (row b<32, k), nkt K-tiles
__device__ __forceinline__ long frag_idx(int b, int k, int nkt){
  return (((long)((b>>4)*nkt + (k>>5)))<<9) + ((b&15) + (((k&31)>>3)<<4))*8 + (k&7);
}

// ================= setup kernels =================
__global__ void k_setup(const f32* __restrict__ c0in, f32* __restrict__ cst,
                        unsigned* __restrict__ cnt){
  int g = blockIdx.x*256 + threadIdx.x;
  if(g < 2*BB*HIDD) cst[g] = c0in[g];
  if(g < 128) cnt[g] = 0;
}

__global__ void k_fill_emb(const f32* __restrict__ emb_table, const int* __restrict__ y,
                           f32* __restrict__ lin){
  int i = blockIdx.x*256 + threadIdx.x;
  if(i >= TT*BB*EMBD) return;
  int e = i & (EMBD-1);
  int tb = i >> 9; int b = tb & 31; int t = tb >> 5;
  int tok = y[b*64 + t];
  lin[(long)(t*BB+b)*LIND + 2048 + e] = emb_table[(long)tok*EMBD + e];
}

__global__ void k_cast_eo(const f32* __restrict__ eo, ushort_t* __restrict__ eob){
  int i = blockIdx.x*256 + threadIdx.x;
  if(i < BB*SS*ENCD) eob[i] = f2bf(eo[i]);
}

// ---- fp32 -> bf16 fragment tiles. perm: src row = (r&3)*1024 + (r>>2). tr: transposed src.
__global__ void k_conv(const f32* __restrict__ src, ushort_t* __restrict__ dst,
                       int ld, int rows, int kmax, int nkt, long ntiles, int tr, int perm){
  long g = (long)blockIdx.x*256 + threadIdx.x;
  long tile = g >> 6;
  if(tile >= ntiles) return;
  int lane = (int)(g & 63);
  int kt = (int)(tile % nkt);
  int rsub = (int)(tile / nkt);
  int r = rsub*16 + (lane&15);
  int k0 = kt*32 + ((lane>>4)<<3);
  int rs = perm ? ((r&3)*1024 + (r>>2)) : r;
  u16x8 v;
  if(!tr && r < rows && (k0+8) <= kmax){
    float4 a = *(const float4*)(src + (long)rs*ld + k0);
    float4 b = *(const float4*)(src + (long)rs*ld + k0 + 4);
    v[0]=f2bf(a.x); v[1]=f2bf(a.y); v[2]=f2bf(a.z); v[3]=f2bf(a.w);
    v[4]=f2bf(b.x); v[5]=f2bf(b.y); v[6]=f2bf(b.z); v[7]=f2bf(b.w);
  } else {
    #pragma unroll
    for(int j=0;j<8;j++){
      int k = k0+j;
      f32 x = 0.f;
      if(r < rows && k < kmax) x = tr ? src[(long)k*ld + rs] : src[(long)rs*ld + k];
      v[j] = f2bf(x);
    }
  }
  *(u16x8*)(dst + (tile<<9) + lane*8) = v;
}

// ---- both-frag MFMA: epb = encf @ Wet^T, bf16 out ldc=1024 (grid 16x8)
__global__ __launch_bounds__(256)
void k_mfma_ep(const ushort_t* __restrict__ At, const ushort_t* __restrict__ Bt,
               ushort_t* __restrict__ Cout){
  const int tid = threadIdx.x, wid = tid >> 6, lane = tid & 63;
  const int wm = wid >> 1, wn = wid & 1;
  const int bm = blockIdx.x, bn = blockIdx.y;
  f32x4 acc[4][4] = {};
  for(int kt=0; kt<32; ++kt){
    bf16x8 af[4], bfr[4];
    #pragma unroll
    for(int i=0;i<4;i++){
      af[i]  = *(const bf16x8*)(At + (((long)(bm*8 + wm*4 + i)*32 + kt)<<9) + lane*8);
      bfr[i] = *(const bf16x8*)(Bt + (((long)(bn*8 + wn*4 + i)*32 + kt)<<9) + lane*8);
    }
    #pragma unroll
    for(int mi=0;mi<4;mi++)
      #pragma unroll
      for(int ni=0;ni<4;ni++)
        acc[mi][ni] = __builtin_amdgcn_mfma_f32_16x16x32_bf16(af[mi], bfr[ni], acc[mi][ni], 0, 0, 0);
  }
  #pragma unroll
  for(int mi=0;mi<4;mi++)
    #pragma unroll
    for(int ni=0;ni<4;ni++)
      #pragma unroll
      for(int r=0;r<4;r++){
        int gm = bm*128 + wm*64 + mi*16 + (lane>>4)*4 + r;
        int gn = bn*128 + wn*64 + ni*16 + (lane&15);
        Cout[(long)gm*1024 + gn] = f2bf(acc[mi][ni][r]);
      }
}

// ================= persistent loop kernel =================
__device__ __forceinline__ void stageA(ushort_t* Ash, const ushort_t* src, int tid){
  __syncthreads();
  u64* d8 = (u64*)Ash;
  const u64* s8 = (const u64*)src;
  #pragma unroll
  for(int c=0;c<8;c++)
    d8[c*1024 + tid] = uc_ld8(&s8[c*1024 + tid]);
  __syncthreads();
}

__device__ __forceinline__ void gemm_pair(const ushort_t* __restrict__ Ash,
    const ushort_t* __restrict__ B0, const ushort_t* __restrict__ B1, int lane,
    f32x4& a00, f32x4& a01, f32x4& a10, f32x4& a11){
  #pragma unroll 4
  for(int kt=0;kt<32;kt++){
    bf16x8 x0 = *(const bf16x8*)(Ash + (kt<<9) + lane*8);
    bf16x8 x1 = *(const bf16x8*)(Ash + 16384 + (kt<<9) + lane*8);
    bf16x8 b0 = *(const bf16x8*)(B0 + (kt<<9) + lane*8);
    bf16x8 b1 = *(const bf16x8*)(B1 + (kt<<9) + lane*8);
    a00 = __builtin_amdgcn_mfma_f32_16x16x32_bf16(x0, b0, a00, 0, 0, 0);
    a01 = __builtin_amdgcn_mfma_f32_16x16x32_bf16(x1, b0, a01, 0, 0, 0);
    a10 = __builtin_amdgcn_mfma_f32_16x16x32_bf16(x0, b1, a10, 0, 0, 0);
    a11 = __builtin_amdgcn_mfma_f32_16x16x32_bf16(x1, b1, a11, 0, 0, 0);
  }
}
__device__ __forceinline__ void gemm_one(const ushort_t* __restrict__ Ash,
    const ushort_t* __restrict__ B0, int lane, f32x4& a0, f32x4& a1){
  #pragma unroll 4
  for(int kt=0;kt<32;kt++){
    bf16x8 b  = *(const bf16x8*)(B0 + (kt<<9) + lane*8);
    bf16x8 x0 = *(const bf16x8*)(Ash + (kt<<9) + lane*8);
    bf16x8 x1 = *(const bf16x8*)(Ash + 16384 + (kt<<9) + lane*8);
    a0 = __builtin_amdgcn_mfma_f32_16x16x32_bf16(x0, b, a0, 0, 0, 0);
    a1 = __builtin_amdgcn_mfma_f32_16x16x32_bf16(x1, b, a1, 0, 0, 0);
  }
}

// fence-free grid barrier: single UC counter line; release = vmcnt(0) per wave.
__device__ __forceinline__ void gbar(unsigned* __restrict__ cnt, unsigned target, int tid){
  asm volatile("s_waitcnt vmcnt(0)" ::: "memory");
  __syncthreads();
  if(tid == 0){
    __hip_atomic_fetch_add(cnt, 1u, __ATOMIC_RELAXED, __HIP_MEMORY_SCOPE_AGENT);
    while(__hip_atomic_load(cnt, __ATOMIC_RELAXED, __HIP_MEMORY_SCOPE_AGENT) < target)
      __builtin_amdgcn_s_sleep(1);
  }
  __syncthreads();
}

// fused LSTM cell half (gate-interleaved acc + shfl butterfly) -- validated r5
__device__ __forceinline__ void cell_half(const f32x4& acc, int bhalf, int lane,
    int ns, int j, f32 bia, const ushort_t* eg_t,
    f32* __restrict__ cst, ushort_t* __restrict__ hdst, f32* __restrict__ lindst){
  int q = (lane&15)&3;
  #pragma unroll
  for(int r=0;r<4;r++){
    int b = bhalf*16 + ((lane>>4)<<2) + r;
    f32 v = acc[r] + bia;
    if(eg_t) v += bf2f(eg_t[(((long)b)<<12) + ns*16 + (lane&15)]);
    f32 x1 = __shfl_xor(v,1), x2 = __shfl_xor(v,2), x3 = __shfl_xor(x1,2);
    f32 gi = q==0? v : q==1? x1 : q==2? x2 : x3;
    f32 gf = q==0? x1: q==1? v  : q==2? x3 : x2;
    f32 gg = q==0? x2: q==1? x3 : q==2? v  : x1;
    f32 go = q==0? x3: q==1? x2 : q==2? x1 : v;
    f32 cold = cst[b*HIDD + j];
    f32 cc = fast_sig(gf)*cold + fast_sig(gi)*fast_tanh(gg);
    f32 hh = fast_sig(go)*fast_tanh(cc);
    if(q == 0){
      cst[b*HIDD + j] = cc;
      uc_st2(hdst + frag_idx(b, j, 32), f2bf(hh));
      if(lindst) lindst[(long)b*LIND + j] = hh;
    }
  }
}

__global__ __launch_bounds__(1024, 4)
void k_loop(char* __restrict__ ws, const f32* __restrict__ vvec,
            const int* __restrict__ maskp,
            const f32* __restrict__ b_ih0, const f32* __restrict__ b_hh0,
            const f32* __restrict__ b_ih1, const f32* __restrict__ b_hh1,
            f32* __restrict__ out){
  f32* lin = (f32*)(ws + OFF_LIN);
  const ushort_t* Wdt   = (const ushort_t*)(ws + OFF_WD);
  const ushort_t* Whh0f = (const ushort_t*)(ws + OFF_WHH0);
  const ushort_t* Wih0cf= (const ushort_t*)(ws + OFF_WIH0C);
  const ushort_t* Wih1f = (const ushort_t*)(ws + OFF_WIH1);
  const ushort_t* Whh1f = (const ushort_t*)(ws + OFF_WHH1);
  const ushort_t* eg    = (const ushort_t*)(ws + OFF_EG);
  const ushort_t* epb   = (const ushort_t*)(ws + OFF_EPB);
  const ushort_t* eob   = (const ushort_t*)(ws + OFF_EOB);
  f32* hwd = (f32*)(ws + OFF_HWD);
  f32* c0  = (f32*)(ws + OFF_C0);
  f32* c1  = (f32*)(ws + OFF_C1);
  ushort_t* h0f  = (ushort_t*)(ws + OFF_H0F);
  ushort_t* h1f  = (ushort_t*)(ws + OFF_H1F);
  ushort_t* ctxf = (ushort_t*)(ws + OFF_CTXF);
  unsigned* cnt  = (unsigned*)(ws + OFF_CNT);
  f32* attw = out + OUT_ATT;

  const int tid = threadIdx.x, wid = tid >> 6, lane = tid & 63;
  const int blk = blockIdx.x;
  const bool isG1 = (blk < 8);
  const bool isG0 = (blk >= 8) && (blk < 16);
  const bool isHW = (blk >= 16) && (blk < 20);

  __shared__ __align__(16) ushort_t Ash[32768];   // 64 KB
  __shared__ f32 hwS[HIDD];
  __shared__ f32 vvS[HIDD];
  __shared__ f32 scs[SS];
  __shared__ f32 wsm[SS];

  vvS[tid] = vvec[tid];

  const int ns0 = isG1 ? (blk*16+wid)*2 : (isG0 ? ((blk-8)*16+wid)*2 : 0);
  const int ns1 = ns0 + 1;
  const int jj = (lane&15)>>2;
  const int q0 = (lane&15)&3;
  const int jc0 = ns0*4+jj, jc1 = ns1*4+jj;
  f32 bia_a = 0.f, bia_b = 0.f;
  if(isG0){ bia_a = b_ih0[q0*HIDD+jc0] + b_hh0[q0*HIDD+jc0];
            bia_b = b_ih0[q0*HIDD+jc1] + b_hh0[q0*HIDD+jc1]; }
  if(isG1){ bia_a = b_ih1[q0*HIDD+jc0] + b_hh1[q0*HIDD+jc0];
            bia_b = b_ih1[q0*HIDD+jc1] + b_hh1[q0*HIDD+jc1]; }

  // persistent gate accumulators: G1 -> g1, G0 -> g0. [slice][bhalf]
  f32x4 gA0 = {0.f,0.f,0.f,0.f}, gA1 = {0.f,0.f,0.f,0.f};
  f32x4 gB0 = {0.f,0.f,0.f,0.f}, gB1 = {0.f,0.f,0.f,0.f};

  // prologue: G0 computes g0h(0) from initial h0
  if(isG0){
    stageA(Ash, h0f, tid);
    gemm_pair(Ash, Whh0f + ((long)ns0<<14), Whh0f + ((long)ns1<<14), lane, gA0, gA1, gB0, gB1);
  }

  unsigned bar = 0;
  for(int t=0; t<TT; ++t){
    // ---------- P1: G1 g1h (fresh); HW hWd ----------
    if(isG1 || isHW) stageA(Ash, h1f, tid);
    if(isG1){
      gA0 = (f32x4){0.f,0.f,0.f,0.f}; gA1 = (f32x4){0.f,0.f,0.f,0.f};
      gB0 = (f32x4){0.f,0.f,0.f,0.f}; gB1 = (f32x4){0.f,0.f,0.f,0.f};
      gemm_pair(Ash, Whh1f + ((long)ns0<<14), Whh1f + ((long)ns1<<14), lane, gA0, gA1, gB0, gB1);
    } else if(isHW){
      int hs = (blk-16)*16 + wid;
      f32x4 da = {0.f,0.f,0.f,0.f}, db = {0.f,0.f,0.f,0.f};
      gemm_one(Ash, Wdt + ((long)hs<<14), lane, da, db);
      int col = hs*16 + (lane&15), r0 = (lane>>4)*4;
      #pragma unroll
      for(int r=0;r<4;r++){
        uc_st4f(&hwd[(r0+r)*HIDD + col], da[r]);
        uc_st4f(&hwd[(16+r0+r)*HIDD + col], db[r]);
      }
    }
    bar += 32; gbar(cnt, bar, tid);

    // ---------- P2: attention (every block owns b = blk) ----------
    {
      int b = blk;
      hwS[tid] = uc_ld4f(&hwd[b*HIDD + tid]);
      __syncthreads();
      #pragma unroll 1
      for(int si=0; si<4; ++si){
        int s = wid*4 + si;
        const ushort_t* ep = epb + ((long)(b*SS+s)<<10);
        f32 p = 0.f;
        #pragma unroll
        for(int i=0;i<16;i++){
          f32 e = bf2f(ep[lane + 64*i]);
          p = __builtin_fmaf(vvS[lane + 64*i], fast_tanh(e + hwS[lane + 64*i]), p);
        }
        #pragma unroll
        for(int off=32; off; off>>=1) p += __shfl_down(p, off);
        if(lane == 0) scs[s] = p;
      }
      __syncthreads();
      if(tid < 64){
        int s = tid;
        f32 x = maskp[b*SS+s] ? scs[s] : -1e9f;
        f32 m = x;
        #pragma unroll
        for(int off=32; off; off>>=1) m = fmaxf(m, __shfl_xor(m, off));
        f32 e = __expf(x - m);
        f32 sum = e;
        #pragma unroll
        for(int off=32; off; off>>=1) sum += __shfl_xor(sum, off);
        f32 w = e/sum;
        wsm[s] = w;
        attw[(long)t*(BB*SS) + b*SS + s] = w;
      }
      __syncthreads();
      if(tid < 256){
        int d0 = tid*4;
        f32 a0=0.f, a1=0.f, a2=0.f, a3=0.f;
        const ushort_t* eo = eob + ((long)b<<16) + d0;
        #pragma unroll 8
        for(int s=0;s<SS;s++){
          u16x4 v = *(const u16x4*)(eo + ((long)s<<10));
          f32 w = wsm[s];
          a0 = __builtin_fmaf(w, bf2f(v[0]), a0);
          a1 = __builtin_fmaf(w, bf2f(v[1]), a1);
          a2 = __builtin_fmaf(w, bf2f(v[2]), a2);
          a3 = __builtin_fmaf(w, bf2f(v[3]), a3);
        }
        *(float4*)(lin + (long)(t*BB+b)*LIND + HIDD + d0) = make_float4(a0,a1,a2,a3);
        u64 pk = (u64)f2bf(a0) | ((u64)f2bf(a1)<<16) | ((u64)f2bf(a2)<<32) | ((u64)f2bf(a3)<<48);
        uc_st8((u64*)(ctxf + frag_idx(b, d0, 32)), pk);
      }
    }
    bar += 32; gbar(cnt, bar, tid);

    // ---------- P3: G0 g0c accumulate + fused cell0 ----------
    if(isG0){
      stageA(Ash, ctxf, tid);
      gemm_pair(Ash, Wih0cf + ((long)ns0<<14), Wih0cf + ((long)ns1<<14), lane, gA0, gA1, gB0, gB1);
      const ushort_t* eg_t = eg + (((long)(t*BB))<<12);
      cell_half(gA0, 0, lane, ns0, jc0, bia_a, eg_t, c0, h0f, (f32*)nullptr);
      cell_half(gA1, 1, lane, ns0, jc0, bia_a, eg_t, c0, h0f, (f32*)nullptr);
      cell_half(gB0, 0, lane, ns1, jc1, bia_b, eg_t, c0, h0f, (f32*)nullptr);
      cell_half(gB1, 1, lane, ns1, jc1, bia_b, eg_t, c0, h0f, (f32*)nullptr);
    }
    bar += 32; gbar(cnt, bar, tid);

    // ---------- P4: G1 g1x+cell1; G0 g0h(t+1) ----------
    if(isG1 || isG0) stageA(Ash, h0f, tid);
    if(isG1){
      gemm_pair(Ash, Wih1f + ((long)ns0<<14), Wih1f + ((long)ns1<<14), lane, gA0, gA1, gB0, gB1);
      f32* lt = lin + (long)t*BB*LIND;
      cell_half(gA0, 0, lane, ns0, jc0, bia_a, (const ushort_t*)nullptr, c1, h1f, lt);
      cell_half(gA1, 1, lane, ns0, jc0, bia_a, (const ushort_t*)nullptr, c1, h1f, lt);
      cell_half(gB0, 0, lane, ns1, jc1, bia_b, (const ushort_t*)nullptr, c1, h1f, lt);
      cell_half(gB1, 1, lane, ns1, jc1, bia_b, (const ushort_t*)nullptr, c1, h1f, lt);
    } else if(isG0){
      gA0 = (f32x4){0.f,0.f,0.f,0.f}; gA1 = (f32x4){0.f,0.f,0.f,0.f};
      gB0 = (f32x4){0.f,0.f,0.f,0.f}; gB1 = (f32x4){0.f,0.f,0.f,0.f};
      gemm_pair(Ash, Whh0f + ((long)ns0<<14), Whh0f + ((long)ns1<<14), lane, gA0, gA1, gB0, gB1);
    }
    bar += 32; gbar(cnt, bar, tid);
  }
}

// ================= phase-2 MFMA GEMM, B converted inline from f32 =================
// EPI1: tanh(x+bias)->hid_bf frags (nkt 68). EPI2: logits scatter. EPI3: bf16 plain (ldc 4096).
template<int NKT, int EPI, bool PERM>
__global__ __launch_bounds__(256)
void k_mfma2(const ushort_t* __restrict__ At, const f32* __restrict__ B,
             int ldb, int nrowsB, int kmaxB,
             const f32* __restrict__ bias, void* __restrict__ Cout){
  const int tid = threadIdx.x, wid = tid >> 6, lane = tid & 63;
  const int wm = wid >> 1, wn = wid & 1;
  const int bm = blockIdx.x, bn = blockIdx.y;
  f32x4 acc[4][4] = {};
  const int rbase = bn*128 + wn*64 + (lane&15);
  const int kb = (lane>>4)*8;
  for(int kt=0; kt<NKT; ++kt){
    bf16x8 af[4], bfr[4];
    #pragma unroll
    for(int i=0;i<4;i++)
      af[i] = *(const bf16x8*)(At + (((long)(bm*8 + wm*4 + i)*NKT + kt)<<9) + lane*8);
    int k0 = kt*32 + kb;
    #pragma unroll
    for(int i=0;i<4;i++){
      int r = rbase + i*16;
      int rs = PERM ? ((r&3)*1024 + (r>>2)) : r;
      u16x8 v;
      if(r < nrowsB && (k0+8) <= kmaxB){
        float4 x = *(const float4*)(B + (long)rs*ldb + k0);
        float4 y = *(const float4*)(B + (long)rs*ldb + k0 + 4);
        v[0]=f2bf(x.x); v[1]=f2bf(x.y); v[2]=f2bf(x.z); v[3]=f2bf(x.w);
        v[4]=f2bf(y.x); v[5]=f2bf(y.y); v[6]=f2bf(y.z); v[7]=f2bf(y.w);
      } else {
        #pragma unroll
        for(int j=0;j<8;j++){
          int k = k0+j;
          f32 xx = (r < nrowsB && k < kmaxB) ? B[(long)rs*ldb + k] : 0.f;
          v[j] = f2bf(xx);
        }
      }
      bfr[i] = *(bf16x8*)&v;
    }
    #pragma unroll
    for(int mi=0;mi<4;mi++)
      #pragma unroll
      for(int ni=0;ni<4;ni++)
        acc[mi][ni] = __builtin_amdgcn_mfma_f32_16x16x32_bf16(af[mi], bfr[ni], acc[mi][ni], 0, 0, 0);
  }
  #pragma unroll
  for(int mi=0;mi<4;mi++){
    #pragma unroll
    for(int ni=0;ni<4;ni++){
      #pragma unroll
      for(int r=0;r<4;r++){
        int gm = bm*128 + wm*64 + mi*16 + (lane>>4)*4 + r;
        int gn = bn*128 + wn*64 + ni*16 + (lane&15);
        f32 x = acc[mi][ni][r];
        if(EPI == 1){
          x = (gn < INTERD) ? fast_tanh(x + bias[gn]) : 0.f;
          ushort_t* hb = (ushort_t*)Cout;
          int msub = gm >> 4, ktile = gn >> 5;
          int lane_a = (gm & 15) + (((gn & 31) >> 3) << 4);
          hb[(((long)(msub*68 + ktile)) << 9) + lane_a*8 + (gn & 7)] = f2bf(x);
        } else if(EPI == 2){
          if(gm < TT*BB){
            int tt = gm >> 5, b = gm & 31;
            ((f32*)Cout)[(long)b*TV + (long)tt*VV + gn] = x + bias[gn];
          }
        } else {
          ((ushort_t*)Cout)[((long)gm<<12) + gn] = f2bf(x);
        }
      }
    }
  }
}

extern "C" void kernel_launch(void* const* d_in, const int* in_sizes, int n_in,
                              void* d_out, int out_size, void* d_ws, size_t ws_size,
                              hipStream_t stream){
  (void)in_sizes; (void)n_in; (void)out_size; (void)ws_size;
  const f32* enc_output = (const f32*)d_in[0];
  const int* mask  = (const int*)d_in[1];
  const int* y     = (const int*)d_in[2];
  const f32* dec_h0= (const f32*)d_in[3];
  const f32* dec_c0= (const f32*)d_in[4];
  const f32* emb   = (const f32*)d_in[5];
  const f32* We    = (const f32*)d_in[6];
  const f32* Wd    = (const f32*)d_in[7];
  const f32* vvec  = (const f32*)d_in[8];
  const f32* W_ih0 = (const f32*)d_in[9];
  const f32* W_hh0 = (const f32*)d_in[10];
  const f32* b_ih0 = (const f32*)d_in[11];
  const f32* b_hh0 = (const f32*)d_in[12];
  const f32* W_ih1 = (const f32*)d_in[13];
  const f32* W_hh1 = (const f32*)d_in[14];
  const f32* b_ih1 = (const f32*)d_in[15];
  const f32* b_hh1 = (const f32*)d_in[16];
  const f32* out_W = (const f32*)d_in[17];
  const f32* out_b = (const f32*)d_in[18];
  const f32* sm_W  = (const f32*)d_in[19];
  const f32* sm_b  = (const f32*)d_in[20];
  f32* out = (f32*)d_out;
  char* ws = (char*)d_ws;

  f32* lin      = (f32*)(ws + OFF_LIN);
  ushort_t* epb = (ushort_t*)(ws + OFF_EPB);
  ushort_t* eob = (ushort_t*)(ws + OFF_EOB);
  ushort_t* encf  = (ushort_t*)(ws + OFF_ENCF);
  ushort_t* wetf  = (ushort_t*)(ws + OFF_WET);
  ushort_t* embf  = (ushort_t*)(ws + OFF_EMBF);
  ushort_t* egbuf = (ushort_t*)(ws + OFF_EG);
  ushort_t* lin_bf = (ushort_t*)(ws + OFF_LINBF);
  ushort_t* hid_bf = (ushort_t*)(ws + OFF_HIDBF);

  // ---- setup ----
  k_setup<<<dim3(256), dim3(256), 0, stream>>>(dec_c0, (f32*)(ws + OFF_C0),
                                               (unsigned*)(ws + OFF_CNT));
  k_fill_emb<<<dim3(4032), dim3(256), 0, stream>>>(emb, y, lin);
  // enc_proj via MFMA: encf frags + We^T frags -> epb (bf16)
  k_conv<<<dim3(1024), dim3(256), 0, stream>>>(enc_output, encf, ENCD, BB*SS, ENCD, 32, 128L*32, 0, 0);
  k_conv<<<dim3(512),  dim3(256), 0, stream>>>(We,         wetf, HIDD, HIDD,  ENCD, 32, 64L*32, 1, 0);
  k_mfma_ep<<<dim3(16,8), dim3(256), 0, stream>>>(encf, wetf, epb);
  k_cast_eo<<<dim3(8192), dim3(256), 0, stream>>>(enc_output, eob);

  // emb frags + embgate = emb @ Wih0e_perm^T -> bf16 [2048][4096] (overwrites encf/wetf)
  k_conv<<<dim3(512),  dim3(256), 0, stream>>>(lin+2048, embf, LIND, TT*BB, 512, 16, 128L*16, 0, 0);
  k_mfma2<16,3,true><<<dim3(16,32), dim3(256), 0, stream>>>(
      embf, W_ih0, 1536, 4096, 512, (const f32*)nullptr, egbuf);

  // ---- weight frags (gate-interleaved perm) ----
  k_conv<<<dim3(512),  dim3(256), 0, stream>>>(Wd,        (ushort_t*)(ws+OFF_WD),    HIDD, HIDD, HIDD, 32, 64L*32, 1, 0);
  k_conv<<<dim3(2048), dim3(256), 0, stream>>>(W_hh0,     (ushort_t*)(ws+OFF_WHH0),  HIDD, 4096, HIDD, 32, 256L*32, 0, 1);
  k_conv<<<dim3(2048), dim3(256), 0, stream>>>(W_ih0+512, (ushort_t*)(ws+OFF_WIH0C), 1536, 4096, HIDD, 32, 256L*32, 0, 1);
  k_conv<<<dim3(2048), dim3(256), 0, stream>>>(W_ih1,     (ushort_t*)(ws+OFF_WIH1),  HIDD, 4096, HIDD, 32, 256L*32, 0, 1);
  k_conv<<<dim3(2048), dim3(256), 0, stream>>>(W_hh1,     (ushort_t*)(ws+OFF_WHH1),  HIDD, 4096, HIDD, 32, 256L*32, 0, 1);
  // initial h frags
  k_conv<<<dim3(16),   dim3(256), 0, stream>>>(dec_h0,       (ushort_t*)(ws+OFF_H0F), HIDD, BB, HIDD, 32, 64, 0, 0);
  k_conv<<<dim3(16),   dim3(256), 0, stream>>>(dec_h0+32768, (ushort_t*)(ws+OFF_H1F), HIDD, BB, HIDD, 32, 64, 0, 0);

  // ---- the 63-step recurrence: 32 persistent blocks x 1024 threads ----
  k_loop<<<dim3(32), dim3(1024), 0, stream>>>(ws, vvec, mask,
      b_ih0, b_hh0, b_ih1, b_hh1, out);

  // ---- phase 2 ----
  k_conv<<<dim3(2560), dim3(256), 0, stream>>>(lin, lin_bf, LIND, TT*BB, LIND, 80, 128L*80, 0, 0);
  k_mfma2<80,1,false><<<dim3(16,17), dim3(256), 0, stream>>>(
      lin_bf, out_W, LIND, INTERD, LIND, out_b, hid_bf);
  k_mfma2<68,2,false><<<dim3(16,250), dim3(256), 0, stream>>>(
      hid_bf, sm_W, INTERD, VV, INTERD, sm_b, out);
}

// Round 7
// 6192.304 us; speedup vs baseline: 1.8705x; 1.8705x over previous
//
#include <hip/hip_runtime.h>
#include <hip/hip_bf16.h>

#define BB 32
#define SS 64
#define TT 63
#define EMBD 512
#define ENCD 1024
#define HIDD 1024
#define VV 32000
#define INTERD 2160
#define LIND 2560
#define TV (TT*VV)
#define OUT_ATT ((long)BB*TT*VV)

typedef float f32;
typedef unsigned short ushort_t;
typedef unsigned long long u64;
typedef __attribute__((ext_vector_type(8))) short bf16x8;
typedef __attribute__((ext_vector_type(4))) float f32x4;
typedef __attribute__((ext_vector_type(8))) unsigned short u16x8;

// ---- ws layout (bytes) ----
#define OFF_LIN   0L
#define OFF_WD    20643840L
#define OFF_WHH0  (OFF_WD + 2097152L)
#define OFF_WIH0C (OFF_WHH0 + 8388608L)
#define OFF_WIH1  (OFF_WIH0C + 8388608L)
#define OFF_WHH1  (OFF_WIH1 + 8388608L)
#define OFF_WEND  (OFF_WHH1 + 8388608L)       /* 56,295,424 */
#define OFF_EG    OFF_WEND                     /* embgate bf16 2048x4096 = 16 MB */
#define OFF_ENCF  OFF_EG                       /* enc frags 4MB, pre-embgate only */
#define OFF_WET   (OFF_EG + 4194304L)          /* We^T frags 2MB, pre-embgate only */
#define OFF_SMCH  OFF_EG                       /* post-loop: sm_W chunk frags <=17.8MB */
#define OFF_EPB   (OFF_EG + 16777216L)         /* enc_proj bf16 4 MB */
#define OFF_EOB   (OFF_EPB + 4194304L)         /* enc_out  bf16 4 MB */
#define OFF_EMBF  (OFF_EOB + 4194304L)         /* emb frags 2 MB */
#define OFF_HWD   (OFF_EMBF + 2097152L)        /* f32 32x1024 (LLC) */
#define OFF_C0    (OFF_HWD + 131072L)
#define OFF_C1    (OFF_C0 + 131072L)
#define OFF_H0F   (OFF_C1 + 131072L)           /* bf16 frags (LLC) */
#define OFF_H1F   (OFF_H0F + 65536L)
#define OFF_CTXF  (OFF_H1F + 65536L)
#define OFF_CNT   (OFF_CTXF + 65536L)
#define OFF_LINBF OFF_WD                        /* post-loop aliases */
#define OFF_HIDBF (OFF_WD + 10485760L)

__device__ __forceinline__ f32 fast_tanh(f32 x){
    f32 e = __expf(2.0f*x);
    return 1.0f - 2.0f/(e+1.0f);
}
__device__ __forceinline__ f32 fast_sig(f32 x){
    return 1.0f/(1.0f+__expf(-x));
}
__device__ __forceinline__ ushort_t f2bf(f32 x){
    __hip_bfloat16 h = __float2bfloat16(x);
    return *(ushort_t*)&h;
}
__device__ __forceinline__ f32 bf2f(ushort_t u){
    unsigned v = ((unsigned)u) << 16;
    return __uint_as_float(v);
}
// ---- device-scope (LLC-coherent) atomics for small scattered state ----
__device__ __forceinline__ void uc_st8(u64* p, u64 v){
  __hip_atomic_store(p, v, __ATOMIC_RELAXED, __HIP_MEMORY_SCOPE_AGENT);
}
__device__ __forceinline__ void uc_st4f(f32* p, f32 v){
  __hip_atomic_store(p, v, __ATOMIC_RELAXED, __HIP_MEMORY_SCOPE_AGENT);
}
__device__ __forceinline__ void uc_st2(ushort_t* p, ushort_t v){
  __hip_atomic_store(p, v, __ATOMIC_RELAXED, __HIP_MEMORY_SCOPE_AGENT);
}

// A-fragment element index for (row b<32, k), nkt K-tiles
__device__ __forceinline__ long frag_idx(int b, int k, int nkt){
  return (((long)((b>>4)*nkt + (k>>5)))<<9) + ((b&15) + (((k&31)>>3)<<4))*8 + (k&7);
}

// ================= setup kernels =================
__global__ void k_setup(const f32* __restrict__ c0in, f32* __restrict__ cst,
                        unsigned* __restrict__ cnt){
  int g = blockIdx.x*256 + threadIdx.x;
  if(g < 2*BB*HIDD) cst[g] = c0in[g];
  if(g < 128) cnt[g] = 0;
}

__global__ void k_fill_emb(const f32* __restrict__ emb_table, const int* __restrict__ y,
                           f32* __restrict__ lin){
  int i = blockIdx.x*256 + threadIdx.x;
  if(i >= TT*BB*EMBD) return;
  int e = i & (EMBD-1);
  int tb = i >> 9; int b = tb & 31; int t = tb >> 5;
  int tok = y[b*64 + t];
  lin[(long)(t*BB+b)*LIND + 2048 + e] = emb_table[(long)tok*EMBD + e];
}

__global__ void k_cast_eo(const f32* __restrict__ eo, ushort_t* __restrict__ eob){
  int i = blockIdx.x*256 + threadIdx.x;
  if(i < BB*SS*ENCD) eob[i] = f2bf(eo[i]);
}

// ---- fp32 -> bf16 fragment tiles. perm: src row = (r&3)*1024 + (r>>2). tr: transposed src.
__global__ void k_conv(const f32* __restrict__ src, ushort_t* __restrict__ dst,
                       int ld, int rows, int kmax, int nkt, long ntiles, int tr, int perm){
  long g = (long)blockIdx.x*256 + threadIdx.x;
  long tile = g >> 6;
  if(tile >= ntiles) return;
  int lane = (int)(g & 63);
  int kt = (int)(tile % nkt);
  int rsub = (int)(tile / nkt);
  int r = rsub*16 + (lane&15);
  int k0 = kt*32 + ((lane>>4)<<3);
  int rs = perm ? ((r&3)*1024 + (r>>2)) : r;
  u16x8 v;
  if(!tr && r < rows && (k0+8) <= kmax){
    float4 a = *(const float4*)(src + (long)rs*ld + k0);
    float4 b = *(const float4*)(src + (long)rs*ld + k0 + 4);
    v[0]=f2bf(a.x); v[1]=f2bf(a.y); v[2]=f2bf(a.z); v[3]=f2bf(a.w);
    v[4]=f2bf(b.x); v[5]=f2bf(b.y); v[6]=f2bf(b.z); v[7]=f2bf(b.w);
  } else {
    #pragma unroll
    for(int j=0;j<8;j++){
      int k = k0+j;
      f32 x = 0.f;
      if(r < rows && k < kmax) x = tr ? src[(long)k*ld + rs] : src[(long)rs*ld + k];
      v[j] = f2bf(x);
    }
  }
  *(u16x8*)(dst + (tile<<9) + lane*8) = v;
}

// ---- both-frag MFMA: epb = encf @ Wet^T, bf16 out ldc=1024 (grid 16x8)
__global__ __launch_bounds__(256)
void k_mfma_ep(const ushort_t* __restrict__ At, const ushort_t* __restrict__ Bt,
               ushort_t* __restrict__ Cout){
  const int tid = threadIdx.x, wid = tid >> 6, lane = tid & 63;
  const int wm = wid >> 1, wn = wid & 1;
  const int bm = blockIdx.x, bn = blockIdx.y;
  f32x4 acc[4][4] = {};
  for(int kt=0; kt<32; ++kt){
    bf16x8 af[4], bfr[4];
    #pragma unroll
    for(int i=0;i<4;i++){
      af[i]  = *(const bf16x8*)(At + (((long)(bm*8 + wm*4 + i)*32 + kt)<<9) + lane*8);
      bfr[i] = *(const bf16x8*)(Bt + (((long)(bn*8 + wn*4 + i)*32 + kt)<<9) + lane*8);
    }
    #pragma unroll
    for(int mi=0;mi<4;mi++)
      #pragma unroll
      for(int ni=0;ni<4;ni++)
        acc[mi][ni] = __builtin_amdgcn_mfma_f32_16x16x32_bf16(af[mi], bfr[ni], acc[mi][ni], 0, 0, 0);
  }
  #pragma unroll
  for(int mi=0;mi<4;mi++)
    #pragma unroll
    for(int ni=0;ni<4;ni++)
      #pragma unroll
      for(int r=0;r<4;r++){
        int gm = bm*128 + wm*64 + mi*16 + (lane>>4)*4 + r;
        int gn = bn*128 + wn*64 + ni*16 + (lane&15);
        Cout[(long)gm*1024 + gn] = f2bf(acc[mi][ni][r]);
      }
}

// ---- both-frag MFMA logits: out[b][t][n0+gn] = A@B^T + bias (grid 16 x nsub/8)
template<int NKT>
__global__ __launch_bounds__(256)
void k_logits(const ushort_t* __restrict__ At, const ushort_t* __restrict__ Bt,
              const f32* __restrict__ bias, f32* __restrict__ out, int n0){
  const int tid = threadIdx.x, wid = tid >> 6, lane = tid & 63;
  const int wm = wid >> 1, wn = wid & 1;
  const int bm = blockIdx.x, bn = blockIdx.y;
  f32x4 acc[4][4] = {};
  for(int kt=0; kt<NKT; ++kt){
    bf16x8 af[4], bfr[4];
    #pragma unroll
    for(int i=0;i<4;i++){
      af[i]  = *(const bf16x8*)(At + (((long)(bm*8 + wm*4 + i)*NKT + kt)<<9) + lane*8);
      bfr[i] = *(const bf16x8*)(Bt + (((long)(bn*8 + wn*4 + i)*NKT + kt)<<9) + lane*8);
    }
    #pragma unroll
    for(int mi=0;mi<4;mi++)
      #pragma unroll
      for(int ni=0;ni<4;ni++)
        acc[mi][ni] = __builtin_amdgcn_mfma_f32_16x16x32_bf16(af[mi], bfr[ni], acc[mi][ni], 0, 0, 0);
  }
  #pragma unroll
  for(int mi=0;mi<4;mi++)
    #pragma unroll
    for(int ni=0;ni<4;ni++)
      #pragma unroll
      for(int r=0;r<4;r++){
        int gm = bm*128 + wm*64 + mi*16 + (lane>>4)*4 + r;
        int gn = bn*128 + wn*64 + ni*16 + (lane&15);
        if(gm < TT*BB){
          int tt = gm >> 5, b = gm & 31;
          out[(long)b*TV + (long)tt*VV + n0 + gn] = acc[mi][ni][r] + bias[gn];
        }
      }
}

// ================= persistent loop kernel =================
// pipelined system-scope (sc0 sc1) staging: 64KB LLC-coherent -> LDS
__device__ __forceinline__ void stage64(ushort_t* Ash, const ushort_t* src, int tid){
  __syncthreads();
  const char* s = (const char*)src + tid*16;
  char* d = (char*)Ash + tid*16;
  #pragma unroll
  for(int it=0; it<2; ++it){
    const char* b = s + it*32768;
    f32x4 t0,t1,t2,t3,t4,t5,t6,t7;
    asm volatile(
      "global_load_dwordx4 %0, %8, off sc0 sc1\n\t"
      "global_load_dwordx4 %1, %9, off sc0 sc1\n\t"
      "global_load_dwordx4 %2, %10, off sc0 sc1\n\t"
      "global_load_dwordx4 %3, %11, off sc0 sc1\n\t"
      "global_load_dwordx4 %4, %12, off sc0 sc1\n\t"
      "global_load_dwordx4 %5, %13, off sc0 sc1\n\t"
      "global_load_dwordx4 %6, %14, off sc0 sc1\n\t"
      "global_load_dwordx4 %7, %15, off sc0 sc1\n\t"
      "s_waitcnt vmcnt(0)"
      : "=&v"(t0),"=&v"(t1),"=&v"(t2),"=&v"(t3),
        "=&v"(t4),"=&v"(t5),"=&v"(t6),"=&v"(t7)
      : "v"(b),"v"(b+4096),"v"(b+8192),"v"(b+12288),
        "v"(b+16384),"v"(b+20480),"v"(b+24576),"v"(b+28672)
      : "memory");
    char* dd = d + it*32768;
    *(f32x4*)dd = t0;           *(f32x4*)(dd+4096)  = t1;
    *(f32x4*)(dd+8192)  = t2;   *(f32x4*)(dd+12288) = t3;
    *(f32x4*)(dd+16384) = t4;   *(f32x4*)(dd+20480) = t5;
    *(f32x4*)(dd+24576) = t6;   *(f32x4*)(dd+28672) = t7;
  }
  __syncthreads();
}

__device__ __forceinline__ void gemm32(const ushort_t* __restrict__ Ash,
    const ushort_t* __restrict__ Bp, int lane, f32x4& a0, f32x4& a1){
  #pragma unroll 4
  for(int kt=0;kt<32;kt++){
    bf16x8 b  = *(const bf16x8*)(Bp + (kt<<9) + lane*8);
    bf16x8 x0 = *(const bf16x8*)(Ash + (kt<<9) + lane*8);
    bf16x8 x1 = *(const bf16x8*)(Ash + 16384 + (kt<<9) + lane*8);
    a0 = __builtin_amdgcn_mfma_f32_16x16x32_bf16(x0, b, a0, 0, 0, 0);
    a1 = __builtin_amdgcn_mfma_f32_16x16x32_bf16(x1, b, a1, 0, 0, 0);
  }
}

// fence-free grid barrier: 8 LLC counter lines; release = vmcnt(0) per wave. (r5-proven)
__device__ __forceinline__ void gbar(unsigned* __restrict__ cnt, unsigned target,
                                     int tid, int blk){
  asm volatile("s_waitcnt vmcnt(0)" ::: "memory");
  __syncthreads();
  if(tid == 0)
    __hip_atomic_fetch_add(&cnt[(blk & 7)*16], 1u,
                           __ATOMIC_RELAXED, __HIP_MEMORY_SCOPE_AGENT);
  if(tid < 64){
    for(;;){
      unsigned v = (tid < 8) ? __hip_atomic_load(&cnt[tid*16],
                       __ATOMIC_RELAXED, __HIP_MEMORY_SCOPE_AGENT) : 0u;
      v += __shfl_xor(v, 1); v += __shfl_xor(v, 2); v += __shfl_xor(v, 4);
      unsigned tot = __shfl(v, 0);
      if(tot >= target) break;
      __builtin_amdgcn_s_sleep(2);
    }
  }
  __syncthreads();
}

// fused LSTM cell half (gate-interleaved acc + shfl butterfly) -- validated r5
__device__ __forceinline__ void cell_half(const f32x4& acc, int bhalf, int lane,
    int ns, int j, f32 bia, const ushort_t* eg_t,
    f32* __restrict__ cst, ushort_t* __restrict__ hdst, f32* __restrict__ lindst){
  int q = (lane&15)&3;
  #pragma unroll
  for(int r=0;r<4;r++){
    int b = bhalf*16 + ((lane>>4)<<2) + r;
    f32 v = acc[r] + bia;
    if(eg_t) v += bf2f(eg_t[(((long)b)<<12) + ns*16 + (lane&15)]);
    f32 x1 = __shfl_xor(v,1), x2 = __shfl_xor(v,2), x3 = __shfl_xor(x1,2);
    f32 gi = q==0? v : q==1? x1 : q==2? x2 : x3;
    f32 gf = q==0? x1: q==1? v  : q==2? x3 : x2;
    f32 gg = q==0? x2: q==1? x3 : q==2? v  : x1;
    f32 go = q==0? x3: q==1? x2 : q==2? x1 : v;
    f32 cold = cst[b*HIDD + j];
    f32 cc = fast_sig(gf)*cold + fast_sig(gi)*fast_tanh(gg);
    f32 hh = fast_sig(go)*fast_tanh(cc);
    if(q == 0){
      cst[b*HIDD + j] = cc;
      uc_st2(hdst + frag_idx(b, j, 32), f2bf(hh));
      if(lindst) lindst[(long)b*LIND + j] = hh;
    }
  }
}

__global__ __launch_bounds__(256, 1)
void k_loop(char* __restrict__ ws, const f32* __restrict__ vvec,
            const int* __restrict__ maskp,
            const f32* __restrict__ b_ih0, const f32* __restrict__ b_hh0,
            const f32* __restrict__ b_ih1, const f32* __restrict__ b_hh1,
            f32* __restrict__ out){
  f32* lin = (f32*)(ws + OFF_LIN);
  const ushort_t* Wdt   = (const ushort_t*)(ws + OFF_WD);
  const ushort_t* Whh0f = (const ushort_t*)(ws + OFF_WHH0);
  const ushort_t* Wih0cf= (const ushort_t*)(ws + OFF_WIH0C);
  const ushort_t* Wih1f = (const ushort_t*)(ws + OFF_WIH1);
  const ushort_t* Whh1f = (const ushort_t*)(ws + OFF_WHH1);
  const ushort_t* eg    = (const ushort_t*)(ws + OFF_EG);
  const ushort_t* epb   = (const ushort_t*)(ws + OFF_EPB);
  const ushort_t* eob   = (const ushort_t*)(ws + OFF_EOB);
  f32* hwd = (f32*)(ws + OFF_HWD);
  f32* c0  = (f32*)(ws + OFF_C0);
  f32* c1  = (f32*)(ws + OFF_C1);
  ushort_t* h0f  = (ushort_t*)(ws + OFF_H0F);
  ushort_t* h1f  = (ushort_t*)(ws + OFF_H1F);
  ushort_t* ctxf = (ushort_t*)(ws + OFF_CTXF);
  unsigned* cnt  = (unsigned*)(ws + OFF_CNT);
  f32* attw = out + OUT_ATT;

  const int tid = threadIdx.x, wid = tid >> 6, lane = tid & 63;
  const int blk = blockIdx.x;
  const int gw = blk*4 + wid;          // 0..255 == ns (gate column slice)
  const int ns = gw;
  const int jj = (lane&15)>>2;
  const int q0 = (lane&15)&3;
  const int jcol = ns*4 + jj;
  const int bidx = q0*HIDD + jcol;

  __shared__ __align__(16) ushort_t Ash[32768];   // 64 KB
  __shared__ f32 hwS[HIDD];
  __shared__ f32 vvS[HIDD];
  __shared__ f32 scs[SS];
  __shared__ f32 wsm[SS];

  for(int i=tid;i<HIDD;i+=256) vvS[i] = vvec[i];

  const f32 bia0 = b_ih0[bidx] + b_hh0[bidx];
  const f32 bia1 = b_ih1[bidx] + b_hh1[bidx];

  // prologue: g0h(0) = h0_init @ Whh0p^T (held in registers)
  stage64(Ash, h0f, tid);
  f32x4 g0a = {0.f,0.f,0.f,0.f}, g0b = {0.f,0.f,0.f,0.f};
  gemm32(Ash, Whh0f + ((long)ns<<14), lane, g0a, g0b);

  unsigned bar = 0;
  for(int t=0; t<TT; ++t){
    // ---------- P1: g1h (regs) + hWd ----------
    stage64(Ash, h1f, tid);
    f32x4 g1a = {0.f,0.f,0.f,0.f}, g1b = {0.f,0.f,0.f,0.f};
    gemm32(Ash, Whh1f + ((long)ns<<14), lane, g1a, g1b);
    if(gw < 64){
      f32x4 da = {0.f,0.f,0.f,0.f}, db = {0.f,0.f,0.f,0.f};
      gemm32(Ash, Wdt + ((long)gw<<14), lane, da, db);
      int col = gw*16 + (lane&15), r0 = (lane>>4)*4;
      #pragma unroll
      for(int r=0;r<4;r++){
        uc_st4f(&hwd[(r0+r)*HIDD + col], da[r]);
        uc_st4f(&hwd[(16+r0+r)*HIDD + col], db[r]);
      }
    }
    bar += 64; gbar(cnt, bar, tid, blk);

    // ---------- P2: attention (blocks 0..31, one per batch row) ----------
    if(blk < 32){
      int b = blk;
      {
        f32x4 hv;
        const f32* hp = hwd + b*HIDD + tid*4;
        asm volatile("global_load_dwordx4 %0, %1, off sc0 sc1\n\ts_waitcnt vmcnt(0)"
                     : "=v"(hv) : "v"(hp) : "memory");
        *(f32x4*)&hwS[tid*4] = hv;
      }
      __syncthreads();
      #pragma unroll 1
      for(int si=0; si<16; ++si){
        int s = wid*16 + si;
        const ushort_t* ep = epb + ((long)(b*SS+s)<<10) + lane*16;
        u16x8 e0 = *(const u16x8*)ep;
        u16x8 e1 = *(const u16x8*)(ep+8);
        f32 p = 0.f;
        #pragma unroll
        for(int j=0;j<8;j++)
          p = __builtin_fmaf(vvS[lane*16+j], fast_tanh(bf2f(e0[j]) + hwS[lane*16+j]), p);
        #pragma unroll
        for(int j=0;j<8;j++)
          p = __builtin_fmaf(vvS[lane*16+8+j], fast_tanh(bf2f(e1[j]) + hwS[lane*16+8+j]), p);
        #pragma unroll
        for(int off=32; off; off>>=1) p += __shfl_down(p, off);
        if(lane == 0) scs[s] = p;
      }
      __syncthreads();
      if(tid < 64){
        int s = tid;
        f32 x = maskp[b*SS+s] ? scs[s] : -1e9f;
        f32 m = x;
        #pragma unroll
        for(int off=32; off; off>>=1) m = fmaxf(m, __shfl_xor(m, off));
        f32 e = __expf(x - m);
        f32 sum = e;
        #pragma unroll
        for(int off=32; off; off>>=1) sum += __shfl_xor(sum, off);
        f32 w = e/sum;
        wsm[s] = w;
        attw[(long)t*(BB*SS) + b*SS + s] = w;
      }
      __syncthreads();
      if(tid < 128){
        int d0 = tid*8;
        f32 a[8] = {0.f,0.f,0.f,0.f,0.f,0.f,0.f,0.f};
        const ushort_t* eo = eob + ((long)b<<16) + d0;
        #pragma unroll 8
        for(int s=0;s<SS;s++){
          u16x8 v = *(const u16x8*)(eo + ((long)s<<10));
          f32 w = wsm[s];
          #pragma unroll
          for(int j=0;j<8;j++) a[j] = __builtin_fmaf(w, bf2f(v[j]), a[j]);
        }
        f32* ld = lin + (long)(t*BB+b)*LIND + HIDD + d0;
        #pragma unroll
        for(int j=0;j<8;j++) ld[j] = a[j];
        u64 lo = (u64)f2bf(a[0]) | ((u64)f2bf(a[1])<<16) | ((u64)f2bf(a[2])<<32) | ((u64)f2bf(a[3])<<48);
        u64 hi = (u64)f2bf(a[4]) | ((u64)f2bf(a[5])<<16) | ((u64)f2bf(a[6])<<32) | ((u64)f2bf(a[7])<<48);
        long fi = frag_idx(b, d0, 32);
        uc_st8((u64*)(ctxf + fi), lo);
        uc_st8((u64*)(ctxf + fi + 4), hi);
      }
    }
    bar += 64; gbar(cnt, bar, tid, blk);

    // ---------- P3: g0c accumulate onto g0 regs + fused cell0 ----------
    stage64(Ash, ctxf, tid);
    gemm32(Ash, Wih0cf + ((long)ns<<14), lane, g0a, g0b);
    {
      const ushort_t* eg_t = eg + (((long)(t*BB))<<12);
      cell_half(g0a, 0, lane, ns, jcol, bia0, eg_t, c0, h0f, (f32*)nullptr);
      cell_half(g0b, 1, lane, ns, jcol, bia0, eg_t, c0, h0f, (f32*)nullptr);
    }
    bar += 64; gbar(cnt, bar, tid, blk);

    // ---------- P4: g1x accumulate + fused cell1 + g0h(t+1) ----------
    stage64(Ash, h0f, tid);
    gemm32(Ash, Wih1f + ((long)ns<<14), lane, g1a, g1b);
    {
      f32* lt = lin + (long)t*BB*LIND;
      cell_half(g1a, 0, lane, ns, jcol, bia1, (const ushort_t*)nullptr, c1, h1f, lt);
      cell_half(g1b, 1, lane, ns, jcol, bia1, (const ushort_t*)nullptr, c1, h1f, lt);
    }
    g0a = (f32x4){0.f,0.f,0.f,0.f}; g0b = (f32x4){0.f,0.f,0.f,0.f};
    gemm32(Ash, Whh0f + ((long)ns<<14), lane, g0a, g0b);
    bar += 64; gbar(cnt, bar, tid, blk);
  }
}

// ================= phase-2 MFMA GEMM, B converted inline from f32 =================
// EPI1: tanh(x+bias)->hid_bf frags (nkt 68). EPI3: bf16 plain (ldc 4096).
template<int NKT, int EPI, bool PERM>
__global__ __launch_bounds__(256)
void k_mfma2(const ushort_t* __restrict__ At, const f32* __restrict__ B,
             int ldb, int nrowsB, int kmaxB,
             const f32* __restrict__ bias, void* __restrict__ Cout){
  const int tid = threadIdx.x, wid = tid >> 6, lane = tid & 63;
  const int wm = wid >> 1, wn = wid & 1;
  const int bm = blockIdx.x, bn = blockIdx.y;
  f32x4 acc[4][4] = {};
  const int rbase = bn*128 + wn*64 + (lane&15);
  const int kb = (lane>>4)*8;
  for(int kt=0; kt<NKT; ++kt){
    bf16x8 af[4], bfr[4];
    #pragma unroll
    for(int i=0;i<4;i++)
      af[i] = *(const bf16x8*)(At + (((long)(bm*8 + wm*4 + i)*NKT + kt)<<9) + lane*8);
    int k0 = kt*32 + kb;
    #pragma unroll
    for(int i=0;i<4;i++){
      int r = rbase + i*16;
      int rs = PERM ? ((r&3)*1024 + (r>>2)) : r;
      u16x8 v;
      if(r < nrowsB && (k0+8) <= kmaxB){
        float4 x = *(const float4*)(B + (long)rs*ldb + k0);
        float4 y = *(const float4*)(B + (long)rs*ldb + k0 + 4);
        v[0]=f2bf(x.x); v[1]=f2bf(x.y); v[2]=f2bf(x.z); v[3]=f2bf(x.w);
        v[4]=f2bf(y.x); v[5]=f2bf(y.y); v[6]=f2bf(y.z); v[7]=f2bf(y.w);
      } else {
        #pragma unroll
        for(int j=0;j<8;j++){
          int k = k0+j;
          f32 xx = (r < nrowsB && k < kmaxB) ? B[(long)rs*ldb + k] : 0.f;
          v[j] = f2bf(xx);
        }
      }
      bfr[i] = *(bf16x8*)&v;
    }
    #pragma unroll
    for(int mi=0;mi<4;mi++)
      #pragma unroll
      for(int ni=0;ni<4;ni++)
        acc[mi][ni] = __builtin_amdgcn_mfma_f32_16x16x32_bf16(af[mi], bfr[ni], acc[mi][ni], 0, 0, 0);
  }
  #pragma unroll
  for(int mi=0;mi<4;mi++){
    #pragma unroll
    for(int ni=0;ni<4;ni++){
      #pragma unroll
      for(int r=0;r<4;r++){
        int gm = bm*128 + wm*64 + mi*16 + (lane>>4)*4 + r;
        int gn = bn*128 + wn*64 + ni*16 + (lane&15);
        f32 x = acc[mi][ni][r];
        if(EPI == 1){
          x = (gn < INTERD) ? fast_tanh(x + bias[gn]) : 0.f;
          ushort_t* hb = (ushort_t*)Cout;
          int msub = gm >> 4, ktile = gn >> 5;
          int lane_a = (gm & 15) + (((gn & 31) >> 3) << 4);
          hb[(((long)(msub*68 + ktile)) << 9) + lane_a*8 + (gn & 7)] = f2bf(x);
        } else {
          ((ushort_t*)Cout)[((long)gm<<12) + gn] = f2bf(x);
        }
      }
    }
  }
}

extern "C" void kernel_launch(void* const* d_in, const int* in_sizes, int n_in,
                              void* d_out, int out_size, void* d_ws, size_t ws_size,
                              hipStream_t stream){
  (void)in_sizes; (void)n_in; (void)out_size; (void)ws_size;
  const f32* enc_output = (const f32*)d_in[0];
  const int* mask  = (const int*)d_in[1];
  const int* y     = (const int*)d_in[2];
  const f32* dec_h0= (const f32*)d_in[3];
  const f32* dec_c0= (const f32*)d_in[4];
  const f32* emb   = (const f32*)d_in[5];
  const f32* We    = (const f32*)d_in[6];
  const f32* Wd    = (const f32*)d_in[7];
  const f32* vvec  = (const f32*)d_in[8];
  const f32* W_ih0 = (const f32*)d_in[9];
  const f32* W_hh0 = (const f32*)d_in[10];
  const f32* b_ih0 = (const f32*)d_in[11];
  const f32* b_hh0 = (const f32*)d_in[12];
  const f32* W_ih1 = (const f32*)d_in[13];
  const f32* W_hh1 = (const f32*)d_in[14];
  const f32* b_ih1 = (const f32*)d_in[15];
  const f32* b_hh1 = (const f32*)d_in[16];
  const f32* out_W = (const f32*)d_in[17];
  const f32* out_b = (const f32*)d_in[18];
  const f32* sm_W  = (const f32*)d_in[19];
  const f32* sm_b  = (const f32*)d_in[20];
  f32* out = (f32*)d_out;
  char* ws = (char*)d_ws;

  f32* lin      = (f32*)(ws + OFF_LIN);
  ushort_t* epb = (ushort_t*)(ws + OFF_EPB);
  ushort_t* eob = (ushort_t*)(ws + OFF_EOB);
  ushort_t* encf  = (ushort_t*)(ws + OFF_ENCF);
  ushort_t* wetf  = (ushort_t*)(ws + OFF_WET);
  ushort_t* embf  = (ushort_t*)(ws + OFF_EMBF);
  ushort_t* egbuf = (ushort_t*)(ws + OFF_EG);
  ushort_t* smch  = (ushort_t*)(ws + OFF_SMCH);
  ushort_t* lin_bf = (ushort_t*)(ws + OFF_LINBF);
  ushort_t* hid_bf = (ushort_t*)(ws + OFF_HIDBF);

  // ---- setup ----
  k_setup<<<dim3(256), dim3(256), 0, stream>>>(dec_c0, (f32*)(ws + OFF_C0),
                                               (unsigned*)(ws + OFF_CNT));
  k_fill_emb<<<dim3(4032), dim3(256), 0, stream>>>(emb, y, lin);
  // enc_proj via MFMA: encf frags + We^T frags -> epb (bf16)
  k_conv<<<dim3(1024), dim3(256), 0, stream>>>(enc_output, encf, ENCD, BB*SS, ENCD, 32, 128L*32, 0, 0);
  k_conv<<<dim3(512),  dim3(256), 0, stream>>>(We,         wetf, HIDD, HIDD,  ENCD, 32, 64L*32, 1, 0);
  k_mfma_ep<<<dim3(16,8), dim3(256), 0, stream>>>(encf, wetf, epb);
  k_cast_eo<<<dim3(8192), dim3(256), 0, stream>>>(enc_output, eob);

  // emb frags + embgate = emb @ Wih0e_perm^T -> bf16 [2048][4096] (overwrites encf/wetf)
  k_conv<<<dim3(512),  dim3(256), 0, stream>>>(lin+2048, embf, LIND, TT*BB, 512, 16, 128L*16, 0, 0);
  k_mfma2<16,3,true><<<dim3(16,32), dim3(256), 0, stream>>>(
      embf, W_ih0, 1536, 4096, 512, (const f32*)nullptr, egbuf);

  // ---- weight frags (gate-interleaved perm) ----
  k_conv<<<dim3(512),  dim3(256), 0, stream>>>(Wd,        (ushort_t*)(ws+OFF_WD),    HIDD, HIDD, HIDD, 32, 64L*32, 1, 0);
  k_conv<<<dim3(2048), dim3(256), 0, stream>>>(W_hh0,     (ushort_t*)(ws+OFF_WHH0),  HIDD, 4096, HIDD, 32, 256L*32, 0, 1);
  k_conv<<<dim3(2048), dim3(256), 0, stream>>>(W_ih0+512, (ushort_t*)(ws+OFF_WIH0C), 1536, 4096, HIDD, 32, 256L*32, 0, 1);
  k_conv<<<dim3(2048), dim3(256), 0, stream>>>(W_ih1,     (ushort_t*)(ws+OFF_WIH1),  HIDD, 4096, HIDD, 32, 256L*32, 0, 1);
  k_conv<<<dim3(2048), dim3(256), 0, stream>>>(W_hh1,     (ushort_t*)(ws+OFF_WHH1),  HIDD, 4096, HIDD, 32, 256L*32, 0, 1);
  // initial h frags
  k_conv<<<dim3(16),   dim3(256), 0, stream>>>(dec_h0,       (ushort_t*)(ws+OFF_H0F), HIDD, BB, HIDD, 32, 64, 0, 0);
  k_conv<<<dim3(16),   dim3(256), 0, stream>>>(dec_h0+32768, (ushort_t*)(ws+OFF_H1F), HIDD, BB, HIDD, 32, 64, 0, 0);

  // ---- the 63-step recurrence: 64 persistent blocks, pipelined sc0sc1 staging ----
  k_loop<<<dim3(64), dim3(256), 0, stream>>>(ws, vvec, mask,
      b_ih0, b_hh0, b_ih1, b_hh1, out);

  // ---- phase 2 ----
  k_conv<<<dim3(2560), dim3(256), 0, stream>>>(lin, lin_bf, LIND, TT*BB, LIND, 80, 128L*80, 0, 0);
  k_mfma2<80,1,false><<<dim3(16,17), dim3(256), 0, stream>>>(
      lin_bf, out_W, LIND, INTERD, LIND, out_b, hid_bf);
  // logits in 8 N-chunks: sm_W chunk -> bf16 frags once, then both-frag MFMA
  for(int c=0; c<8; ++c){
    int n0 = c*4096;
    int rows = (c<7) ? 4096 : 3328;
    int nsub = rows >> 4;
    long ntiles = (long)nsub*68;
    k_conv<<<dim3((unsigned)((ntiles*64+255)/256)), dim3(256), 0, stream>>>(
        sm_W + (long)n0*INTERD, smch, INTERD, rows, INTERD, 68, ntiles, 0, 0);
    k_logits<68><<<dim3(16, nsub/8), dim3(256), 0, stream>>>(
        hid_bf, smch, sm_b + n0, out, n0);
  }
}

// Round 8
// 4949.714 us; speedup vs baseline: 2.3400x; 1.2510x over previous
//
#include <hip/hip_runtime.h>
#include <hip/hip_bf16.h>

#define BB 32
#define SS 64
#define TT 63
#define EMBD 512
#define ENCD 1024
#define HIDD 1024
#define VV 32000
#define INTERD 2160
#define LIND 2560
#define TV (TT*VV)
#define OUT_ATT ((long)BB*TT*VV)

typedef float f32;
typedef unsigned short ushort_t;
typedef unsigned long long u64;
typedef __attribute__((ext_vector_type(8))) short bf16x8;
typedef __attribute__((ext_vector_type(4))) float f32x4;
typedef __attribute__((ext_vector_type(8))) unsigned short u16x8;

// ---- ws layout (bytes), total ~82.3 MB ----
#define OFF_LINBF 0L                           /* lin_bf frags 128msub x 80kt = 10,485,760 */
#define OFF_WD    10485760L
#define OFF_WHH0  (OFF_WD + 2097152L)
#define OFF_WIH0C (OFF_WHH0 + 8388608L)
#define OFF_WIH1  (OFF_WIH0C + 8388608L)
#define OFF_WHH1  (OFF_WIH1 + 8388608L)
#define OFF_WEND  (OFF_WHH1 + 8388608L)        /* 46,137,344 */
#define OFF_EG    OFF_WEND                      /* embgate bf16 2048x4096 = 16 MB */
#define OFF_ENCF  OFF_EG                        /* enc frags 4MB, pre-embgate only */
#define OFF_WET   (OFF_EG + 4194304L)           /* We^T frags 2MB, pre-embgate only */
#define OFF_SMCH  OFF_EG                        /* post-loop: sm_W chunk frags <=17.8MB */
#define OFF_EPB   (OFF_EG + 16777216L)          /* enc_proj bf16 4 MB */
#define OFF_EOB   (OFF_EPB + 4194304L)          /* enc_out  bf16 4 MB */
#define OFF_EMBF  (OFF_EOB + 4194304L)          /* emb frags 2 MB */
#define OFF_HWD   (OFF_EMBF + 2097152L)         /* f32 32x1024 (UC, reused addr) */
#define OFF_C0    (OFF_HWD + 131072L)
#define OFF_C1    (OFF_C0 + 131072L)
#define OFF_CNT   (OFF_C1 + 131072L)            /* 4 KB counters */
#define OFF_H0B   (OFF_CNT + 4096L)             /* 64 slots x 64KB = 4,194,304 (per-step) */
#define OFF_H1B   (OFF_H0B + 4194304L)          /* 64 slots */
#define OFF_CXB   (OFF_H1B + 4194304L)          /* 63 slots x 64KB = 4,128,768 */
#define OFF_HIDBF OFF_WD                         /* post-loop alias over weights */

__device__ __forceinline__ f32 fast_tanh(f32 x){
    f32 e = __expf(2.0f*x);
    return 1.0f - 2.0f/(e+1.0f);
}
__device__ __forceinline__ f32 fast_sig(f32 x){
    return 1.0f/(1.0f+__expf(-x));
}
__device__ __forceinline__ ushort_t f2bf(f32 x){
    __hip_bfloat16 h = __float2bfloat16(x);
    return *(ushort_t*)&h;
}
__device__ __forceinline__ f32 bf2f(ushort_t u){
    unsigned v = ((unsigned)u) << 16;
    return __uint_as_float(v);
}
// ---- device-scope (LLC write-through) stores for cross-block state ----
__device__ __forceinline__ void uc_st8(u64* p, u64 v){
  __hip_atomic_store(p, v, __ATOMIC_RELAXED, __HIP_MEMORY_SCOPE_AGENT);
}
__device__ __forceinline__ void uc_st4f(f32* p, f32 v){
  __hip_atomic_store(p, v, __ATOMIC_RELAXED, __HIP_MEMORY_SCOPE_AGENT);
}
__device__ __forceinline__ void uc_st2(ushort_t* p, ushort_t v){
  __hip_atomic_store(p, v, __ATOMIC_RELAXED, __HIP_MEMORY_SCOPE_AGENT);
}

// fragment element index for (row, k), nkt K-tiles (generic row)
__device__ __forceinline__ long frag_idx(int row, int k, int nkt){
  return (((long)((row>>4)*nkt + (k>>5)))<<9) + ((row&15) + (((k&31)>>3)<<4))*8 + (k&7);
}

// ================= setup kernels =================
__global__ void k_setup(const f32* __restrict__ c0in, f32* __restrict__ cst,
                        unsigned* __restrict__ cnt){
  int g = blockIdx.x*256 + threadIdx.x;
  if(g < 2*BB*HIDD) cst[g] = c0in[g];
  if(g < 128) cnt[g] = 0;
}

// gather embeddings -> embf frags (nkt16) AND lin_bf frags (nkt80, k offset 2048)
__global__ void k_fill_emb(const f32* __restrict__ emb_table, const int* __restrict__ y,
                           ushort_t* __restrict__ embf, ushort_t* __restrict__ lin_bf){
  int i = blockIdx.x*256 + threadIdx.x;
  if(i >= TT*BB*EMBD) return;
  int e = i & (EMBD-1);
  int tb = i >> 9; int b = tb & 31; int t = tb >> 5;
  int tok = y[b*64 + t];
  ushort_t bv = f2bf(emb_table[(long)tok*EMBD + e]);
  int row = t*32 + b;
  embf[frag_idx(row, e, 16)] = bv;
  lin_bf[frag_idx(row, 2048 + e, 80)] = bv;
}

__global__ void k_cast_eo(const f32* __restrict__ eo, ushort_t* __restrict__ eob){
  int i = blockIdx.x*256 + threadIdx.x;
  if(i < BB*SS*ENCD) eob[i] = f2bf(eo[i]);
}

// ---- fp32 -> bf16 fragment tiles. perm: src row = (r&3)*1024 + (r>>2). tr: transposed src.
__global__ void k_conv(const f32* __restrict__ src, ushort_t* __restrict__ dst,
                       int ld, int rows, int kmax, int nkt, long ntiles, int tr, int perm){
  long g = (long)blockIdx.x*256 + threadIdx.x;
  long tile = g >> 6;
  if(tile >= ntiles) return;
  int lane = (int)(g & 63);
  int kt = (int)(tile % nkt);
  int rsub = (int)(tile / nkt);
  int r = rsub*16 + (lane&15);
  int k0 = kt*32 + ((lane>>4)<<3);
  int rs = perm ? ((r&3)*1024 + (r>>2)) : r;
  u16x8 v;
  if(!tr && r < rows && (k0+8) <= kmax){
    float4 a = *(const float4*)(src + (long)rs*ld + k0);
    float4 b = *(const float4*)(src + (long)rs*ld + k0 + 4);
    v[0]=f2bf(a.x); v[1]=f2bf(a.y); v[2]=f2bf(a.z); v[3]=f2bf(a.w);
    v[4]=f2bf(b.x); v[5]=f2bf(b.y); v[6]=f2bf(b.z); v[7]=f2bf(b.w);
  } else {
    #pragma unroll
    for(int j=0;j<8;j++){
      int k = k0+j;
      f32 x = 0.f;
      if(r < rows && k < kmax) x = tr ? src[(long)k*ld + rs] : src[(long)rs*ld + k];
      v[j] = f2bf(x);
    }
  }
  *(u16x8*)(dst + (tile<<9) + lane*8) = v;
}

// ---- both-frag MFMA: epb = encf @ Wet^T, bf16 out ldc=1024 (grid 16x8)
__global__ __launch_bounds__(256)
void k_mfma_ep(const ushort_t* __restrict__ At, const ushort_t* __restrict__ Bt,
               ushort_t* __restrict__ Cout){
  const int tid = threadIdx.x, wid = tid >> 6, lane = tid & 63;
  const int wm = wid >> 1, wn = wid & 1;
  const int bm = blockIdx.x, bn = blockIdx.y;
  f32x4 acc[4][4] = {};
  for(int kt=0; kt<32; ++kt){
    bf16x8 af[4], bfr[4];
    #pragma unroll
    for(int i=0;i<4;i++){
      af[i]  = *(const bf16x8*)(At + (((long)(bm*8 + wm*4 + i)*32 + kt)<<9) + lane*8);
      bfr[i] = *(const bf16x8*)(Bt + (((long)(bn*8 + wn*4 + i)*32 + kt)<<9) + lane*8);
    }
    #pragma unroll
    for(int mi=0;mi<4;mi++)
      #pragma unroll
      for(int ni=0;ni<4;ni++)
        acc[mi][ni] = __builtin_amdgcn_mfma_f32_16x16x32_bf16(af[mi], bfr[ni], acc[mi][ni], 0, 0, 0);
  }
  #pragma unroll
  for(int mi=0;mi<4;mi++)
    #pragma unroll
    for(int ni=0;ni<4;ni++)
      #pragma unroll
      for(int r=0;r<4;r++){
        int gm = bm*128 + wm*64 + mi*16 + (lane>>4)*4 + r;
        int gn = bn*128 + wn*64 + ni*16 + (lane&15);
        Cout[(long)gm*1024 + gn] = f2bf(acc[mi][ni][r]);
      }
}

// ---- both-frag MFMA logits: out[b][t][n0+gn] = A@B^T + bias (grid 16 x nsub/8)
template<int NKT>
__global__ __launch_bounds__(256)
void k_logits(const ushort_t* __restrict__ At, const ushort_t* __restrict__ Bt,
              const f32* __restrict__ bias, f32* __restrict__ out, int n0){
  const int tid = threadIdx.x, wid = tid >> 6, lane = tid & 63;
  const int wm = wid >> 1, wn = wid & 1;
  const int bm = blockIdx.x, bn = blockIdx.y;
  f32x4 acc[4][4] = {};
  for(int kt=0; kt<NKT; ++kt){
    bf16x8 af[4], bfr[4];
    #pragma unroll
    for(int i=0;i<4;i++){
      af[i]  = *(const bf16x8*)(At + (((long)(bm*8 + wm*4 + i)*NKT + kt)<<9) + lane*8);
      bfr[i] = *(const bf16x8*)(Bt + (((long)(bn*8 + wn*4 + i)*NKT + kt)<<9) + lane*8);
    }
    #pragma unroll
    for(int mi=0;mi<4;mi++)
      #pragma unroll
      for(int ni=0;ni<4;ni++)
        acc[mi][ni] = __builtin_amdgcn_mfma_f32_16x16x32_bf16(af[mi], bfr[ni], acc[mi][ni], 0, 0, 0);
  }
  #pragma unroll
  for(int mi=0;mi<4;mi++)
    #pragma unroll
    for(int ni=0;ni<4;ni++)
      #pragma unroll
      for(int r=0;r<4;r++){
        int gm = bm*128 + wm*64 + mi*16 + (lane>>4)*4 + r;
        int gn = bn*128 + wn*64 + ni*16 + (lane&15);
        if(gm < TT*BB){
          int tt = gm >> 5, b = gm & 31;
          out[(long)b*TV + (long)tt*VV + n0 + gn] = acc[mi][ni][r] + bias[gn];
        }
      }
}

// ================= persistent loop kernel =================
// stage 64KB via PLAIN CACHED loads -- safe because src address is per-step fresh
// (never L2-cached stale); producers wrote through to LLC before the barrier.
__device__ __forceinline__ void stage64(ushort_t* Ash, const ushort_t* src, int tid){
  __syncthreads();
  const f32x4* s = (const f32x4*)src;
  f32x4* d = (f32x4*)Ash;
  #pragma unroll
  for(int c=0;c<16;c++) d[c*256 + tid] = s[c*256 + tid];
  __syncthreads();
}

__device__ __forceinline__ void gemm32(const ushort_t* __restrict__ Ash,
    const ushort_t* __restrict__ Bp, int lane, f32x4& a0, f32x4& a1){
  #pragma unroll 4
  for(int kt=0;kt<32;kt++){
    bf16x8 b  = *(const bf16x8*)(Bp + (kt<<9) + lane*8);
    bf16x8 x0 = *(const bf16x8*)(Ash + (kt<<9) + lane*8);
    bf16x8 x1 = *(const bf16x8*)(Ash + 16384 + (kt<<9) + lane*8);
    a0 = __builtin_amdgcn_mfma_f32_16x16x32_bf16(x0, b, a0, 0, 0, 0);
    a1 = __builtin_amdgcn_mfma_f32_16x16x32_bf16(x1, b, a1, 0, 0, 0);
  }
}

// fence-free grid barrier: 8 LLC counter lines; release = vmcnt(0) per wave. (r5/r7-proven)
__device__ __forceinline__ void gbar(unsigned* __restrict__ cnt, unsigned target,
                                     int tid, int blk){
  asm volatile("s_waitcnt vmcnt(0)" ::: "memory");
  __syncthreads();
  if(tid == 0)
    __hip_atomic_fetch_add(&cnt[(blk & 7)*16], 1u,
                           __ATOMIC_RELAXED, __HIP_MEMORY_SCOPE_AGENT);
  if(tid < 64){
    for(;;){
      unsigned v = (tid < 8) ? __hip_atomic_load(&cnt[tid*16],
                       __ATOMIC_RELAXED, __HIP_MEMORY_SCOPE_AGENT) : 0u;
      v += __shfl_xor(v, 1); v += __shfl_xor(v, 2); v += __shfl_xor(v, 4);
      unsigned tot = __shfl(v, 0);
      if(tot >= target) break;
      __builtin_amdgcn_s_sleep(2);
    }
  }
  __syncthreads();
}

// fused LSTM cell half; hdst = per-step h slot (LLC store); ldst = lin_bf row-block or null
__device__ __forceinline__ void cell_half(const f32x4& acc, int bhalf, int lane,
    int ns, int j, f32 bia, const ushort_t* eg_t,
    f32* __restrict__ cst, ushort_t* __restrict__ hdst, ushort_t* __restrict__ ldst){
  int q = (lane&15)&3;
  #pragma unroll
  for(int r=0;r<4;r++){
    int b = bhalf*16 + ((lane>>4)<<2) + r;
    f32 v = acc[r] + bia;
    if(eg_t) v += bf2f(eg_t[(((long)b)<<12) + ns*16 + (lane&15)]);
    f32 x1 = __shfl_xor(v,1), x2 = __shfl_xor(v,2), x3 = __shfl_xor(x1,2);
    f32 gi = q==0? v : q==1? x1 : q==2? x2 : x3;
    f32 gf = q==0? x1: q==1? v  : q==2? x3 : x2;
    f32 gg = q==0? x2: q==1? x3 : q==2? v  : x1;
    f32 go = q==0? x3: q==1? x2 : q==2? x1 : v;
    f32 cold = cst[b*HIDD + j];
    f32 cc = fast_sig(gf)*cold + fast_sig(gi)*fast_tanh(gg);
    f32 hh = fast_sig(go)*fast_tanh(cc);
    if(q == 0){
      cst[b*HIDD + j] = cc;
      ushort_t hb = f2bf(hh);
      uc_st2(hdst + frag_idx(b, j, 32), hb);
      if(ldst) ldst[frag_idx(b, j, 80)] = hb;   // plain store, post-loop consumer
    }
  }
}

__global__ __launch_bounds__(256, 1)
void k_loop(char* __restrict__ ws, const f32* __restrict__ vvec,
            const int* __restrict__ maskp,
            const f32* __restrict__ b_ih0, const f32* __restrict__ b_hh0,
            const f32* __restrict__ b_ih1, const f32* __restrict__ b_hh1,
            f32* __restrict__ out){
  ushort_t* lin_bf = (ushort_t*)(ws + OFF_LINBF);
  const ushort_t* Wdt   = (const ushort_t*)(ws + OFF_WD);
  const ushort_t* Whh0f = (const ushort_t*)(ws + OFF_WHH0);
  const ushort_t* Wih0cf= (const ushort_t*)(ws + OFF_WIH0C);
  const ushort_t* Wih1f = (const ushort_t*)(ws + OFF_WIH1);
  const ushort_t* Whh1f = (const ushort_t*)(ws + OFF_WHH1);
  const ushort_t* eg    = (const ushort_t*)(ws + OFF_EG);
  const ushort_t* epb   = (const ushort_t*)(ws + OFF_EPB);
  const ushort_t* eob   = (const ushort_t*)(ws + OFF_EOB);
  f32* hwd = (f32*)(ws + OFF_HWD);
  f32* c0  = (f32*)(ws + OFF_C0);
  f32* c1  = (f32*)(ws + OFF_C1);
  ushort_t* h0b = (ushort_t*)(ws + OFF_H0B);   // 64 slots x 32768 ushorts
  ushort_t* h1b = (ushort_t*)(ws + OFF_H1B);
  ushort_t* cxb = (ushort_t*)(ws + OFF_CXB);   // 63 slots
  unsigned* cnt  = (unsigned*)(ws + OFF_CNT);
  f32* attw = out + OUT_ATT;

  const int tid = threadIdx.x, wid = tid >> 6, lane = tid & 63;
  const int blk = blockIdx.x;
  const int gw = blk*4 + wid;          // 0..255 == ns (gate column slice)
  const int ns = gw;
  const int jj = (lane&15)>>2;
  const int q0 = (lane&15)&3;
  const int jcol = ns*4 + jj;
  const int bidx = q0*HIDD + jcol;

  __shared__ __align__(16) ushort_t Ash[32768];   // 64 KB
  __shared__ f32 hwS[HIDD];
  __shared__ f32 vvS[HIDD];
  __shared__ f32 scs[SS];
  __shared__ f32 wsm[SS];

  for(int i=tid;i<HIDD;i+=256) vvS[i] = vvec[i];

  const f32 bia0 = b_ih0[bidx] + b_hh0[bidx];
  const f32 bia1 = b_ih1[bidx] + b_hh1[bidx];

  // prologue: g0h(0) = h0_init @ Whh0p^T (held in registers)
  stage64(Ash, h0b, tid);
  f32x4 g0a = {0.f,0.f,0.f,0.f}, g0b = {0.f,0.f,0.f,0.f};
  gemm32(Ash, Whh0f + ((long)ns<<14), lane, g0a, g0b);

  unsigned bar = 0;
  for(int t=0; t<TT; ++t){
    // ---------- P1: g1h (regs) + hWd ----------
    stage64(Ash, h1b + (long)t*32768, tid);
    f32x4 g1a = {0.f,0.f,0.f,0.f}, g1b = {0.f,0.f,0.f,0.f};
    gemm32(Ash, Whh1f + ((long)ns<<14), lane, g1a, g1b);
    if(gw < 64){
      f32x4 da = {0.f,0.f,0.f,0.f}, db = {0.f,0.f,0.f,0.f};
      gemm32(Ash, Wdt + ((long)gw<<14), lane, da, db);
      int col = gw*16 + (lane&15), r0 = (lane>>4)*4;
      #pragma unroll
      for(int r=0;r<4;r++){
        uc_st4f(&hwd[(r0+r)*HIDD + col], da[r]);
        uc_st4f(&hwd[(16+r0+r)*HIDD + col], db[r]);
      }
    }
    bar += 64; gbar(cnt, bar, tid, blk);

    // ---------- P2: attention (blocks 0..31, one per batch row) ----------
    if(blk < 32){
      int b = blk;
      {
        f32x4 hv;
        const f32* hp = hwd + b*HIDD + tid*4;   // reused addr -> must stay uncached
        asm volatile("global_load_dwordx4 %0, %1, off sc0 sc1\n\ts_waitcnt vmcnt(0)"
                     : "=v"(hv) : "v"(hp) : "memory");
        *(f32x4*)&hwS[tid*4] = hv;
      }
      __syncthreads();
      #pragma unroll 1
      for(int si=0; si<16; ++si){
        int s = wid*16 + si;
        const ushort_t* ep = epb + ((long)(b*SS+s)<<10) + lane*16;
        u16x8 e0 = *(const u16x8*)ep;
        u16x8 e1 = *(const u16x8*)(ep+8);
        f32 p = 0.f;
        #pragma unroll
        for(int j=0;j<8;j++)
          p = __builtin_fmaf(vvS[lane*16+j], fast_tanh(bf2f(e0[j]) + hwS[lane*16+j]), p);
        #pragma unroll
        for(int j=0;j<8;j++)
          p = __builtin_fmaf(vvS[lane*16+8+j], fast_tanh(bf2f(e1[j]) + hwS[lane*16+8+j]), p);
        #pragma unroll
        for(int off=32; off; off>>=1) p += __shfl_down(p, off);
        if(lane == 0) scs[s] = p;
      }
      __syncthreads();
      if(tid < 64){
        int s = tid;
        f32 x = maskp[b*SS+s] ? scs[s] : -1e9f;
        f32 m = x;
        #pragma unroll
        for(int off=32; off; off>>=1) m = fmaxf(m, __shfl_xor(m, off));
        f32 e = __expf(x - m);
        f32 sum = e;
        #pragma unroll
        for(int off=32; off; off>>=1) sum += __shfl_xor(sum, off);
        f32 w = e/sum;
        wsm[s] = w;
        attw[(long)t*(BB*SS) + b*SS + s] = w;
      }
      __syncthreads();
      if(tid < 128){
        int d0 = tid*8;
        f32 a[8] = {0.f,0.f,0.f,0.f,0.f,0.f,0.f,0.f};
        const ushort_t* eo = eob + ((long)b<<16) + d0;
        #pragma unroll 8
        for(int s=0;s<SS;s++){
          u16x8 v = *(const u16x8*)(eo + ((long)s<<10));
          f32 w = wsm[s];
          #pragma unroll
          for(int j=0;j<8;j++) a[j] = __builtin_fmaf(w, bf2f(v[j]), a[j]);
        }
        u16x8 cf;
        #pragma unroll
        for(int j=0;j<8;j++) cf[j] = f2bf(a[j]);
        // fresh per-step slot for P3 consumers (LLC write-through)
        u64 lo = (u64)(unsigned short)cf[0] | ((u64)(unsigned short)cf[1]<<16)
               | ((u64)(unsigned short)cf[2]<<32) | ((u64)(unsigned short)cf[3]<<48);
        u64 hi = (u64)(unsigned short)cf[4] | ((u64)(unsigned short)cf[5]<<16)
               | ((u64)(unsigned short)cf[6]<<32) | ((u64)(unsigned short)cf[7]<<48);
        long fi = frag_idx(b, d0, 32);
        ushort_t* cx_t = cxb + (long)t*32768;
        uc_st8((u64*)(cx_t + fi), lo);
        uc_st8((u64*)(cx_t + fi + 4), hi);
        // lin_bf frag for phase-2 (plain store)
        *(u16x8*)(lin_bf + (long)t*81920 + frag_idx(b, 1024 + d0, 80)) = cf;
      }
    }
    bar += 64; gbar(cnt, bar, tid, blk);

    // ---------- P3: g0c accumulate onto g0 regs + fused cell0 ----------
    stage64(Ash, cxb + (long)t*32768, tid);
    gemm32(Ash, Wih0cf + ((long)ns<<14), lane, g0a, g0b);
    {
      const ushort_t* eg_t = eg + (((long)(t*BB))<<12);
      ushort_t* h0_t = h0b + (long)(t+1)*32768;
      cell_half(g0a, 0, lane, ns, jcol, bia0, eg_t, c0, h0_t, (ushort_t*)nullptr);
      cell_half(g0b, 1, lane, ns, jcol, bia0, eg_t, c0, h0_t, (ushort_t*)nullptr);
    }
    bar += 64; gbar(cnt, bar, tid, blk);

    // ---------- P4: g1x accumulate + fused cell1 + g0h(t+1) ----------
    stage64(Ash, h0b + (long)(t+1)*32768, tid);
    gemm32(Ash, Wih1f + ((long)ns<<14), lane, g1a, g1b);
    {
      ushort_t* h1_t = h1b + (long)(t+1)*32768;
      ushort_t* lt = lin_bf + (long)t*81920;
      cell_half(g1a, 0, lane, ns, jcol, bia1, (const ushort_t*)nullptr, c1, h1_t, lt);
      cell_half(g1b, 1, lane, ns, jcol, bia1, (const ushort_t*)nullptr, c1, h1_t, lt);
    }
    g0a = (f32x4){0.f,0.f,0.f,0.f}; g0b = (f32x4){0.f,0.f,0.f,0.f};
    gemm32(Ash, Whh0f + ((long)ns<<14), lane, g0a, g0b);
    bar += 64; gbar(cnt, bar, tid, blk);
  }
}

// ================= phase-2 MFMA GEMM, B converted inline from f32 =================
// EPI1: tanh(x+bias)->hid_bf frags (nkt 68). EPI3: bf16 plain (ldc 4096).
template<int NKT, int EPI, bool PERM>
__global__ __launch_bounds__(256)
void k_mfma2(const ushort_t* __restrict__ At, const f32* __restrict__ B,
             int ldb, int nrowsB, int kmaxB,
             const f32* __restrict__ bias, void* __restrict__ Cout){
  const int tid = threadIdx.x, wid = tid >> 6, lane = tid & 63;
  const int wm = wid >> 1, wn = wid & 1;
  const int bm = blockIdx.x, bn = blockIdx.y;
  f32x4 acc[4][4] = {};
  const int rbase = bn*128 + wn*64 + (lane&15);
  const int kb = (lane>>4)*8;
  for(int kt=0; kt<NKT; ++kt){
    bf16x8 af[4], bfr[4];
    #pragma unroll
    for(int i=0;i<4;i++)
      af[i] = *(const bf16x8*)(At + (((long)(bm*8 + wm*4 + i)*NKT + kt)<<9) + lane*8);
    int k0 = kt*32 + kb;
    #pragma unroll
    for(int i=0;i<4;i++){
      int r = rbase + i*16;
      int rs = PERM ? ((r&3)*1024 + (r>>2)) : r;
      u16x8 v;
      if(r < nrowsB && (k0+8) <= kmaxB){
        float4 x = *(const float4*)(B + (long)rs*ldb + k0);
        float4 y = *(const float4*)(B + (long)rs*ldb + k0 + 4);
        v[0]=f2bf(x.x); v[1]=f2bf(x.y); v[2]=f2bf(x.z); v[3]=f2bf(x.w);
        v[4]=f2bf(y.x); v[5]=f2bf(y.y); v[6]=f2bf(y.z); v[7]=f2bf(y.w);
      } else {
        #pragma unroll
        for(int j=0;j<8;j++){
          int k = k0+j;
          f32 xx = (r < nrowsB && k < kmaxB) ? B[(long)rs*ldb + k] : 0.f;
          v[j] = f2bf(xx);
        }
      }
      bfr[i] = *(bf16x8*)&v;
    }
    #pragma unroll
    for(int mi=0;mi<4;mi++)
      #pragma unroll
      for(int ni=0;ni<4;ni++)
        acc[mi][ni] = __builtin_amdgcn_mfma_f32_16x16x32_bf16(af[mi], bfr[ni], acc[mi][ni], 0, 0, 0);
  }
  #pragma unroll
  for(int mi=0;mi<4;mi++){
    #pragma unroll
    for(int ni=0;ni<4;ni++){
      #pragma unroll
      for(int r=0;r<4;r++){
        int gm = bm*128 + wm*64 + mi*16 + (lane>>4)*4 + r;
        int gn = bn*128 + wn*64 + ni*16 + (lane&15);
        f32 x = acc[mi][ni][r];
        if(EPI == 1){
          x = (gn < INTERD) ? fast_tanh(x + bias[gn]) : 0.f;
          ushort_t* hb = (ushort_t*)Cout;
          int msub = gm >> 4, ktile = gn >> 5;
          int lane_a = (gm & 15) + (((gn & 31) >> 3) << 4);
          hb[(((long)(msub*68 + ktile)) << 9) + lane_a*8 + (gn & 7)] = f2bf(x);
        } else {
          ((ushort_t*)Cout)[((long)gm<<12) + gn] = f2bf(x);
        }
      }
    }
  }
}

extern "C" void kernel_launch(void* const* d_in, const int* in_sizes, int n_in,
                              void* d_out, int out_size, void* d_ws, size_t ws_size,
                              hipStream_t stream){
  (void)in_sizes; (void)n_in; (void)out_size; (void)ws_size;
  const f32* enc_output = (const f32*)d_in[0];
  const int* mask  = (const int*)d_in[1];
  const int* y     = (const int*)d_in[2];
  const f32* dec_h0= (const f32*)d_in[3];
  const f32* dec_c0= (const f32*)d_in[4];
  const f32* emb   = (const f32*)d_in[5];
  const f32* We    = (const f32*)d_in[6];
  const f32* Wd    = (const f32*)d_in[7];
  const f32* vvec  = (const f32*)d_in[8];
  const f32* W_ih0 = (const f32*)d_in[9];
  const f32* W_hh0 = (const f32*)d_in[10];
  const f32* b_ih0 = (const f32*)d_in[11];
  const f32* b_hh0 = (const f32*)d_in[12];
  const f32* W_ih1 = (const f32*)d_in[13];
  const f32* W_hh1 = (const f32*)d_in[14];
  const f32* b_ih1 = (const f32*)d_in[15];
  const f32* b_hh1 = (const f32*)d_in[16];
  const f32* out_W = (const f32*)d_in[17];
  const f32* out_b = (const f32*)d_in[18];
  const f32* sm_W  = (const f32*)d_in[19];
  const f32* sm_b  = (const f32*)d_in[20];
  f32* out = (f32*)d_out;
  char* ws = (char*)d_ws;

  ushort_t* lin_bf = (ushort_t*)(ws + OFF_LINBF);
  ushort_t* epb = (ushort_t*)(ws + OFF_EPB);
  ushort_t* eob = (ushort_t*)(ws + OFF_EOB);
  ushort_t* encf  = (ushort_t*)(ws + OFF_ENCF);
  ushort_t* wetf  = (ushort_t*)(ws + OFF_WET);
  ushort_t* embf  = (ushort_t*)(ws + OFF_EMBF);
  ushort_t* egbuf = (ushort_t*)(ws + OFF_EG);
  ushort_t* smch  = (ushort_t*)(ws + OFF_SMCH);
  ushort_t* hid_bf = (ushort_t*)(ws + OFF_HIDBF);

  // ---- setup ----
  k_setup<<<dim3(256), dim3(256), 0, stream>>>(dec_c0, (f32*)(ws + OFF_C0),
                                               (unsigned*)(ws + OFF_CNT));
  k_fill_emb<<<dim3(4032), dim3(256), 0, stream>>>(emb, y, embf, lin_bf);
  // enc_proj via MFMA: encf frags + We^T frags -> epb (bf16)
  k_conv<<<dim3(1024), dim3(256), 0, stream>>>(enc_output, encf, ENCD, BB*SS, ENCD, 32, 128L*32, 0, 0);
  k_conv<<<dim3(512),  dim3(256), 0, stream>>>(We,         wetf, HIDD, HIDD,  ENCD, 32, 64L*32, 1, 0);
  k_mfma_ep<<<dim3(16,8), dim3(256), 0, stream>>>(encf, wetf, epb);
  k_cast_eo<<<dim3(8192), dim3(256), 0, stream>>>(enc_output, eob);

  // embgate = emb @ Wih0e_perm^T -> bf16 [2048][4096] (overwrites encf/wetf)
  k_mfma2<16,3,true><<<dim3(16,32), dim3(256), 0, stream>>>(
      embf, W_ih0, 1536, 4096, 512, (const f32*)nullptr, egbuf);

  // ---- weight frags (gate-interleaved perm) ----
  k_conv<<<dim3(512),  dim3(256), 0, stream>>>(Wd,        (ushort_t*)(ws+OFF_WD),    HIDD, HIDD, HIDD, 32, 64L*32, 1, 0);
  k_conv<<<dim3(2048), dim3(256), 0, stream>>>(W_hh0,     (ushort_t*)(ws+OFF_WHH0),  HIDD, 4096, HIDD, 32, 256L*32, 0, 1);
  k_conv<<<dim3(2048), dim3(256), 0, stream>>>(W_ih0+512, (ushort_t*)(ws+OFF_WIH0C), 1536, 4096, HIDD, 32, 256L*32, 0, 1);
  k_conv<<<dim3(2048), dim3(256), 0, stream>>>(W_ih1,     (ushort_t*)(ws+OFF_WIH1),  HIDD, 4096, HIDD, 32, 256L*32, 0, 1);
  k_conv<<<dim3(2048), dim3(256), 0, stream>>>(W_hh1,     (ushort_t*)(ws+OFF_WHH1),  HIDD, 4096, HIDD, 32, 256L*32, 0, 1);
  // initial h frags -> slot 0 of per-step buffers
  k_conv<<<dim3(16),   dim3(256), 0, stream>>>(dec_h0,       (ushort_t*)(ws+OFF_H0B), HIDD, BB, HIDD, 32, 64, 0, 0);
  k_conv<<<dim3(16),   dim3(256), 0, stream>>>(dec_h0+32768, (ushort_t*)(ws+OFF_H1B), HIDD, BB, HIDD, 32, 64, 0, 0);

  // ---- the 63-step recurrence: 64 persistent blocks, per-step cached state slots ----
  k_loop<<<dim3(64), dim3(256), 0, stream>>>(ws, vvec, mask,
      b_ih0, b_hh0, b_ih1, b_hh1, out);

  // ---- phase 2 (lin_bf written directly by the loop; no conversion pass) ----
  k_mfma2<80,1,false><<<dim3(16,17), dim3(256), 0, stream>>>(
      lin_bf, out_W, LIND, INTERD, LIND, out_b, hid_bf);
  // logits in 8 N-chunks: sm_W chunk -> bf16 frags once, then both-frag MFMA
  for(int c=0; c<8; ++c){
    int n0 = c*4096;
    int rows = (c<7) ? 4096 : 3328;
    int nsub = rows >> 4;
    long ntiles = (long)nsub*68;
    k_conv<<<dim3((unsigned)((ntiles*64+255)/256)), dim3(256), 0, stream>>>(
        sm_W + (long)n0*INTERD, smch, INTERD, rows, INTERD, 68, ntiles, 0, 0);
    k_logits<68><<<dim3(16, nsub/8), dim3(256), 0, stream>>>(
        hid_bf, smch, sm_b + n0, out, n0);
  }
}